// Round 4
// baseline (304.840 us; speedup 1.0000x reference)
//
#include <hip/hip_runtime.h>
#include <hip/hip_bf16.h>

typedef __attribute__((ext_vector_type(8))) short short8;
typedef __attribute__((ext_vector_type(4))) float floatx4;

#define TT 8            // t-values per block
#define XS_PITCH 264    // per-c pitch (TT*32 + 8) -> bank-conflict break, 16B-aligned
#define KCP 200         // XAs row pitch (192 + 8), 400B rows keep b128 reads 16B-aligned

__device__ __forceinline__ float bf2f(unsigned short u) {
    unsigned int xx = ((unsigned int)u) << 16;
    return __uint_as_float(xx);
}
__device__ __forceinline__ unsigned short f2bf(float f) {
    unsigned int xx = __float_as_uint(f);
    unsigned int r = (xx + 0x7fffu + ((xx >> 16) & 1u)) >> 16;
    return (unsigned short)r;
}

// LDS: Xs 33792 + AsL 6144 + XAs 12800 + colsum 384 + s/b2 512 + bc 768 = 54400 B <= 64K
__global__ __launch_bounds__(512) void gcn_fused(
    const float* __restrict__ x,  const float* __restrict__ A,
    const float* __restrict__ PA, const float* __restrict__ Wc,
    const float* __restrict__ bc, const float* __restrict__ gamma_,
    const float* __restrict__ beta_, const float* __restrict__ mean_,
    const float* __restrict__ var_, float* __restrict__ out)
{
#if defined(__gfx950__)
    __shared__ __align__(16) unsigned short Xs[64 * XS_PITCH];   // x tile bf16, [c][t][vpad32]
    __shared__ __align__(16) unsigned short AsL[96 * 32];        // Aeff^T bf16: [kw][vpad32]
    __shared__ __align__(16) unsigned short XAs[32 * KCP];       // bf16 [w][kc=k*64+c]
    __shared__ float colsumL[96];
    __shared__ float sL[64], b2L[64], bcL[192];

    const int tid = threadIdx.x;
    const int n  = blockIdx.x >> 5;
    const int t0 = (blockIdx.x & 31) * TT;

    const float* xn = x + (size_t)n * 64 * 256 * 25;
    for (int idx = tid; idx < 64 * TT * 32; idx += 512) {
        int c = idx >> 8, r = idx & 255;        // TT*32 = 256
        int t = r >> 5, v = r & 31;
        float val = 0.f;
        if (v < 25) val = xn[(c * 256 + t0 + t) * 25 + v];
        Xs[c * XS_PITCH + r] = f2bf(val);
    }
    for (int idx = tid; idx < 96 * 32; idx += 512) {
        int kw = idx >> 5, v = idx & 31;
        int k = kw >> 5, w = kw & 31;
        unsigned short val = 0;
        if (w < 25 && v < 25) {
            int ai = (k * 25 + v) * 25 + w;
            val = f2bf(A[ai] * PA[ai]);
        }
        AsL[kw * 32 + v] = val;
    }
    if (tid < 96) {
        int k = tid >> 5, w = tid & 31;
        float s = 0.f;
        if (w < 25)
            for (int v = 0; v < 25; ++v) {
                int ai = (k * 25 + v) * 25 + w;
                s += A[ai] * PA[ai];
            }
        colsumL[tid] = s;
    }
    if (tid < 64) {
        float sc = gamma_[tid] * rsqrtf(var_[tid] + 1e-5f);
        sL[tid]  = sc;
        b2L[tid] = beta_[tid] - mean_[tid] * sc;
    }
    if (tid < 192) bcL[tid] = bc[tid];
    __syncthreads();

    const int wave = tid >> 6, lane = tid & 63;
    const int l15 = lane & 15, quad = lane >> 4;

    // stage A': ntile over c (0..3), 3 mtiles over kw
    const int ntA = wave & 3, wmA = wave >> 2;
    short8 aA[3];
#pragma unroll
    for (int ii = 0; ii < 3; ++ii) {
        int mt = wmA + 2 * ii;
        aA[ii] = *(const short8*)&AsL[(mt * 16 + l15) * 32 + quad * 8];
    }

    // stage B': cotile (0..3) x wtile (0..1); W2[co][k*64+c] = Wc[k*64+co][c], f32->bf16
    const int cot = wave & 3, wt = wave >> 2;
    union U8 { short8 v; unsigned short s[8]; };
    short8 wf[6];
#pragma unroll
    for (int ks = 0; ks < 6; ++ks) {
        int k = ks >> 1;
        int co = cot * 16 + l15;
        int cpart = (ks & 1) * 32 + quad * 8;
        const float* wp = &Wc[(k * 64 + co) * 64 + cpart];
        U8 u;
#pragma unroll
        for (int j = 0; j < 8; ++j) u.s[j] = f2bf(wp[j]);
        wf[ks] = u.v;
    }

    for (int t = 0; t < TT; ++t) {
        // ---- A': XA^T(kw,c) = Aeff^T(kw,v) @ X_t(v,c), contraction over v ----
        short8 xb = *(const short8*)&Xs[(ntA * 16 + l15) * XS_PITCH + t * 32 + quad * 8];
        floatx4 fr[3];
#pragma unroll
        for (int ii = 0; ii < 3; ++ii) {
            floatx4 z0 = {0.f, 0.f, 0.f, 0.f};
            fr[ii] = __builtin_amdgcn_mfma_f32_16x16x32_bf16(aA[ii], xb, z0, 0, 0, 0);
        }
        __syncthreads();   // prev iteration's B' reads of XAs complete
#pragma unroll
        for (int ii = 0; ii < 3; ++ii) {
            int mt = wmA + 2 * ii;
#pragma unroll
            for (int r = 0; r < 4; ++r) {
                int kw = mt * 16 + quad * 4 + r;     // D row
                int w = kw & 31, k = kw >> 5;
                XAs[w * KCP + k * 64 + ntA * 16 + l15] = f2bf(fr[ii][r]);
            }
        }
        __syncthreads();

        // ---- B': Z(co,w) = W2(co,kc) @ XA(kc,w) ----
        floatx4 zacc = {0.f, 0.f, 0.f, 0.f};
        const unsigned short* xr = &XAs[(wt * 16 + l15) * KCP];
#pragma unroll
        for (int ks = 0; ks < 6; ++ks) {
            short8 bfr = *(const short8*)&xr[ks * 32 + quad * 8];
            zacc = __builtin_amdgcn_mfma_f32_16x16x32_bf16(wf[ks], bfr, zacc, 0, 0, 0);
        }

        // ---- epilogue: conv-bias via colsum, BN, residual, relu ----
        int w = wt * 16 + l15;
        if (w < 25) {
            float cs0 = colsumL[w], cs1 = colsumL[32 + w], cs2 = colsumL[64 + w];
#pragma unroll
            for (int r = 0; r < 4; ++r) {
                int co = cot * 16 + quad * 4 + r;
                float bterm = bcL[co] * cs0 + bcL[64 + co] * cs1 + bcL[128 + co] * cs2;
                float xres = bf2f(Xs[co * XS_PITCH + t * 32 + w]);
                float val = sL[co] * (zacc[r] + bterm) + b2L[co] + xres;
                out[((size_t)(n * 64 + co) * 256 + t0 + t) * 25 + w] = fmaxf(val, 0.f);
            }
        }
    }
#else
    // non-gfx950 compilation pass: empty body (never executes on the bench chip)
    (void)x; (void)A; (void)PA; (void)Wc; (void)bc;
    (void)gamma_; (void)beta_; (void)mean_; (void)var_; (void)out;
#endif
}

extern "C" void kernel_launch(void* const* d_in, const int* in_sizes, int n_in,
                              void* d_out, int out_size, void* d_ws, size_t ws_size,
                              hipStream_t stream) {
    (void)in_sizes; (void)n_in; (void)d_ws; (void)ws_size; (void)out_size;
    gcn_fused<<<dim3(64 * 32), dim3(512), 0, stream>>>(
        (const float*)d_in[0],   // x
        (const float*)d_in[1],   // A
        (const float*)d_in[2],   // PA
        (const float*)d_in[3],   // Wc
        (const float*)d_in[4],   // bc
        (const float*)d_in[5],   // gamma
        (const float*)d_in[6],   // beta
        (const float*)d_in[7],   // mean
        (const float*)d_in[8],   // var
        (float*)d_out);
}